// Round 1
// baseline (4495.663 us; speedup 1.0000x reference)
//
#include <hip/hip_runtime.h>
#include <math.h>

// SemiCurrSinkhornKnopp_stable on MI355X: persistent cooperative-style kernel.
// B=4, n=2048, k=512 (+1 slack). K = exp(-C/eps) = softmax(logits)^10 kept in LDS.
// 512 WGs x 256 thr; 16 rows/WG; 2 grid barriers per iteration (DIY tree barrier).

#define NWG   512
#define NTHR  256
#define NROW  2048
#define KC    512
#define KP1   513
#define SLABS 128          // row slabs per batch (128 * 16 = 2048)
#define RPW   16           // rows per workgroup
#define EPSI  0.1f
#define IEPS  10.0f
#define FI    0.90909090909090906f     // gamma/(gamma+eps), f32-rounded like jnp
#define FIM1  (-0.09090909090909094f)  // fi - 1.0
#define TINY  1.1920928955078125e-07f  // finfo(f32).eps
#define PA    (1.0f/2048.0f)
#define PBR   (0.5f/512.0f)
#define PBS   0.5f
#define STABT 1.0e8f
#define STOPE 1.0e-6f
#define ITMAX 50

__device__ __forceinline__ float wsum(float v) {
#pragma unroll
  for (int m = 32; m > 0; m >>= 1) v += __shfl_xor(v, m, 64);
  return v;
}
__device__ __forceinline__ float wmaxf(float v) {
#pragma unroll
  for (int m = 32; m > 0; m >>= 1) v = fmaxf(v, __shfl_xor(v, m, 64));
  return v;
}

// Two-level grid barrier: 32 leaf counters (64B apart) x 16 WGs, root of 32,
// generation flag. Counters monotonically increase; host memsets to 0 each launch.
__device__ __forceinline__ void gbar(unsigned* leaf, unsigned* root, unsigned* gen) {
  __syncthreads();
  if (threadIdx.x == 0) {
    unsigned g = __hip_atomic_load(gen, __ATOMIC_RELAXED, __HIP_MEMORY_SCOPE_AGENT);
    unsigned* lc = leaf + ((blockIdx.x >> 4) << 4);   // stride 16 u32 = 64B
    unsigned p1 = __hip_atomic_fetch_add(lc, 1u, __ATOMIC_ACQ_REL, __HIP_MEMORY_SCOPE_AGENT);
    if ((p1 & 15u) == 15u) {
      unsigned p2 = __hip_atomic_fetch_add(root, 1u, __ATOMIC_ACQ_REL, __HIP_MEMORY_SCOPE_AGENT);
      if ((p2 & 31u) == 31u)
        __hip_atomic_store(gen, g + 1u, __ATOMIC_RELEASE, __HIP_MEMORY_SCOPE_AGENT);
    }
    while (__hip_atomic_load(gen, __ATOMIC_ACQUIRE, __HIP_MEMORY_SCOPE_AGENT) == g)
      __builtin_amdgcn_s_sleep(1);
  }
  __syncthreads();
}

__global__ __launch_bounds__(NTHR, 2)
void sinkhorn_kernel(const float* __restrict__ logits, float* __restrict__ out,
                     unsigned char* __restrict__ ws, float* __restrict__ partials) {
  const int tid  = threadIdx.x;
  const int wg   = blockIdx.x;
  const int lane = tid & 63;
  const int wid  = tid >> 6;
  const int bat  = wg >> 7;       // batch 0..3
  const int slab = wg & 127;      // row slab within batch

  unsigned* leaf   = (unsigned*)(ws);          // 2048B
  unsigned* root   = (unsigned*)(ws + 2048);
  unsigned* gen    = (unsigned*)(ws + 2052);
  float*    err_sq = (float*)(ws + 2056);      // [2]
  unsigned* stmax  = (unsigned*)(ws + 2064);   // [2] float bits (all values >= 0)
  float*    amaxa  = (float*)(ws + 2080);      // [512]
  float*    bn_g   = (float*)(ws + 4128);      // [4*513]

  __shared__ float Klds[RPW][KP1];
  __shared__ float ev[KP1], vv[KP1], bb[KP1], lb[KP1], ww[KC];
  __shared__ float u_s[RPW], kap[RPW], a_s[RPW], alp[RPW];
  __shared__ float wred[4];
  __shared__ float colred[4][64];

  // ---------------- phase 0: init state + build K in LDS ----------------
  for (int j = tid; j < KP1; j += NTHR) {
    vv[j] = 0.f; bb[j] = 1.f / 513.f; lb[j] = 1.f / 513.f;
    if (j < KC) ww[j] = 1.f;
  }
  if (tid < RPW) { u_s[tid] = 0.f; kap[tid] = 1.f; a_s[tid] = 0.f; alp[tid] = 0.f; }

  const size_t rowg0 = (size_t)bat * NROW + (size_t)slab * RPW;
  for (int r = wid; r < RPW; r += 4) {
    const float* lp = logits + (rowg0 + (size_t)r) * KC;
    float x[8];
    float mx = -INFINITY;
#pragma unroll
    for (int m = 0; m < 8; ++m) { x[m] = lp[lane + (m << 6)]; mx = fmaxf(mx, x[m]); }
    mx = wmaxf(mx);
    float sm = 0.f;
#pragma unroll
    for (int m = 0; m < 8; ++m) sm += expf(x[m] - mx);
    sm = wsum(sm);
    float lse = mx + logf(sm);
#pragma unroll
    for (int m = 0; m < 8; ++m) Klds[r][lane + (m << 6)] = expf((x[m] - lse) * IEPS);
    if (lane == 0) Klds[r][KC] = 1.f;   // slack column: C=0 -> K=1
  }
  __syncthreads();

  // ---------------- iterations ----------------
  float err_state = 1.f;
  int   stabled = 0;
  int   pend = -1;

  auto apply = [&](int par_) {
    float esq = err_sq[par_];
    int stab = (__uint_as_float(stmax[par_]) > STABT) ? 1 : 0;
    for (int j = tid; j < KP1; j += NTHR) {
      float bnj = bn_g[bat * KP1 + j];
      if (stab) {
        vv[j] += EPSI * logf(bnj + TINY);
        if (j < KC) ww[j] *= powf(fmaxf(bnj, TINY), FIM1);
        bb[j] = 1.f;
      } else {
        bb[j] = bnj;
      }
      lb[j] = bnj;
    }
    if (stab && tid < RPW) {
      u_s[tid] += EPSI * logf(a_s[tid]);
      kap[tid] = expf(u_s[tid] * IEPS);
    }
    err_state = sqrtf(esq);
    stabled = stab;
    __syncthreads();
  };

  for (int t = 0; t < ITMAX; ++t) {
    if (pend >= 0) { apply(pend); pend = -1; }
    if (!(err_state > STOPE)) break;     // uniform across grid

    // ---- phase A: ev, row sums -> a, alpha; col partials ----
    for (int j = tid; j < KP1; j += NTHR) ev[j] = expf(vv[j] * IEPS) * bb[j];
    __syncthreads();

    float wamax = 0.f;
    for (int r = wid; r < RPW; r += 4) {
      float s = 0.f;
#pragma unroll
      for (int m = 0; m < 8; ++m) { int j = lane + (m << 6); s += Klds[r][j] * ev[j]; }
      if (lane == 0) s += Klds[r][KC] * ev[KC];
      s = wsum(s);
      if (lane == 0) {
        float av = PA / (kap[r] * s);
        a_s[r] = av; alp[r] = kap[r] * av;
        wamax = fmaxf(wamax, av);
      }
    }
    if (lane == 0) wred[wid] = wamax;
    __syncthreads();
    if (tid == 0) amaxa[wg] = fmaxf(fmaxf(wred[0], wred[1]), fmaxf(wred[2], wred[3]));

    for (int j = tid; j < KP1; j += NTHR) {
      float acc = 0.f;
#pragma unroll
      for (int r = 0; r < RPW; ++r) acc += Klds[r][j] * alp[r];
      partials[((size_t)bat * SLABS + slab) * KP1 + j] = acc;
    }
    gbar(leaf, root, gen);

    // ---- phase B: column sums -> bn, err, stab-max ----
    const int par = t & 1;
    {
      int j = (slab < 9) ? (slab * 64 + lane) : KP1;   // WG-uniform owner branch
      float acc = 0.f;
      if (j < KP1) {
        const float* pbase = partials + (size_t)bat * SLABS * KP1 + j;
        for (int s = wid * 32; s < wid * 32 + 32; ++s) acc += pbase[(size_t)s * KP1];
      }
      colred[wid][lane] = acc;
      __syncthreads();
      if (slab < 9 && wid == 0) {
        float esql = 0.f, bmx = 0.f;
        if (j < KP1) {
          float tot = colred[0][lane] + colred[1][lane] + colred[2][lane] + colred[3][lane];
          float c = expf(vv[j] * IEPS) * tot;
          float pb = (j < KC) ? PBR : PBS;
          float bnr = pb / c;
          float bnj = (j < KC) ? powf(fmaxf(bnr, TINY), FI) * ww[j] : bnr;
          bn_g[bat * KP1 + j] = bnj;
          float d = bnj - lb[j];
          esql = d * d; bmx = bnj;
        }
        esql = wsum(esql); bmx = wmaxf(bmx);
        if (lane == 0) {
          atomicAdd(&err_sq[par], esql);
          atomicMax(&stmax[par], __float_as_uint(bmx));
        }
      }
    }
    if (wg == 9 && wid == 1) {   // global a-max (amaxa written in phase A, pre-S1)
      float m = 0.f;
      for (int i = lane; i < NWG; i += 64) m = fmaxf(m, amaxa[i]);
      m = wmaxf(m);
      if (lane == 0) atomicMax(&stmax[par], __float_as_uint(m));
    }
    if (wg == 10 && tid == 0) {  // zero next-parity accumulators (consumed pre-S1)
      __hip_atomic_store(&err_sq[par ^ 1], 0.f, __ATOMIC_RELAXED, __HIP_MEMORY_SCOPE_AGENT);
      __hip_atomic_store(&stmax[par ^ 1], 0u, __ATOMIC_RELAXED, __HIP_MEMORY_SCOPE_AGENT);
    }
    gbar(leaf, root, gen);
    pend = par;
  }
  if (pend >= 0) { apply(pend); pend = -1; }

  // ---------------- final: plan = (stabled ? Q : a*Q*b^T) * n, drop slack ----------------
  for (int j = tid; j < KP1; j += NTHR) ev[j] = expf(vv[j] * IEPS);
  __syncthreads();
  for (int r = wid; r < RPW; r += 4) {
    float* op = out + (rowg0 + (size_t)r) * KC;
    float kr = kap[r], ar = a_s[r];
#pragma unroll
    for (int m = 0; m < 8; ++m) {
      int j = lane + (m << 6);
      float Q = kr * Klds[r][j] * ev[j];
      float val = stabled ? Q : (ar * Q * bb[j]);
      op[j] = val * 2048.0f;
    }
  }
}

extern "C" void kernel_launch(void* const* d_in, const int* in_sizes, int n_in,
                              void* d_out, int out_size, void* d_ws, size_t ws_size,
                              hipStream_t stream) {
  (void)in_sizes; (void)n_in; (void)out_size; (void)ws_size;
  const float* logits = (const float*)d_in[0];
  float* out = (float*)d_out;
  // barrier counters + gen + err/stab scalars must start at 0 each launch
  hipMemsetAsync(d_ws, 0, 2080, stream);
  // partials buffer (4*128*513 floats = 1.05MB) carved from d_out; it is only
  // overwritten by the final plan store, which happens after the last barrier.
  sinkhorn_kernel<<<dim3(NWG), dim3(NTHR), 0, stream>>>(
      logits, out, (unsigned char*)d_ws, (float*)d_out);
}

// Round 3
// 2055.881 us; speedup vs baseline: 2.1867x; 2.1867x over previous
//
#include <hip/hip_runtime.h>
#include <math.h>

// SemiCurrSinkhornKnopp_stable on MI355X: persistent cooperative-style kernel.
// B=4, n=2048, k=512 (+1 slack). K = exp(-C/eps) = softmax(logits)^10 kept in LDS.
// 512 WGs x 256 thr; 16 rows/WG; 2 grid barriers per iteration (DIY tree barrier).
// R2/R3: barrier fixed — relaxed polling + single release/acquire fence per WG
// (R1 polled with ACQUIRE@AGENT = buffer_inv sc1 per poll = L2-invalidate storm,
//  44us/barrier; machine 99% idle). R3: __builtin_amdgcn_fence spelling.

#define NWG   512
#define NTHR  256
#define NROW  2048
#define KC    512
#define KP1   513
#define SLABS 128          // row slabs per batch (128 * 16 = 2048)
#define RPW   16           // rows per workgroup
#define EPSI  0.1f
#define IEPS  10.0f
#define FI    0.90909090909090906f     // gamma/(gamma+eps), f32-rounded like jnp
#define FIM1  (-0.09090909090909094f)  // fi - 1.0
#define TINY  1.1920928955078125e-07f  // finfo(f32).eps
#define PA    (1.0f/2048.0f)
#define PBR   (0.5f/512.0f)
#define PBS   0.5f
#define STABT 1.0e8f
#define STOPE 1.0e-6f
#define ITMAX 50

__device__ __forceinline__ float wsum(float v) {
#pragma unroll
  for (int m = 32; m > 0; m >>= 1) v += __shfl_xor(v, m, 64);
  return v;
}
__device__ __forceinline__ float wmaxf(float v) {
#pragma unroll
  for (int m = 32; m > 0; m >>= 1) v = fmaxf(v, __shfl_xor(v, m, 64));
  return v;
}

// Two-level grid barrier: 32 leaf counters (64B apart) x 16 WGs, root of 32,
// generation flag. Counters monotonically increase; host memsets to 0 each launch.
// All atomics RELAXED; one release fence before arrive (publish this WG's writes),
// one acquire fence after release from spin (invalidate L1+L2 once).
__device__ __forceinline__ void gbar(unsigned* leaf, unsigned* root, unsigned* gen) {
  __syncthreads();
  if (threadIdx.x == 0) {
    __builtin_amdgcn_fence(__ATOMIC_RELEASE, "agent");
    unsigned g = __hip_atomic_load(gen, __ATOMIC_RELAXED, __HIP_MEMORY_SCOPE_AGENT);
    unsigned* lc = leaf + ((blockIdx.x >> 4) << 4);   // stride 16 u32 = 64B
    unsigned p1 = __hip_atomic_fetch_add(lc, 1u, __ATOMIC_RELAXED, __HIP_MEMORY_SCOPE_AGENT);
    if ((p1 & 15u) == 15u) {
      unsigned p2 = __hip_atomic_fetch_add(root, 1u, __ATOMIC_RELAXED, __HIP_MEMORY_SCOPE_AGENT);
      if ((p2 & 31u) == 31u)
        __hip_atomic_store(gen, g + 1u, __ATOMIC_RELAXED, __HIP_MEMORY_SCOPE_AGENT);
    }
    while (__hip_atomic_load(gen, __ATOMIC_RELAXED, __HIP_MEMORY_SCOPE_AGENT) == g)
      __builtin_amdgcn_s_sleep(4);
    __builtin_amdgcn_fence(__ATOMIC_ACQUIRE, "agent");
  }
  __syncthreads();
}

__global__ __launch_bounds__(NTHR, 2)
void sinkhorn_kernel(const float* __restrict__ logits, float* __restrict__ out,
                     unsigned char* __restrict__ ws, float* __restrict__ partials) {
  const int tid  = threadIdx.x;
  const int wg   = blockIdx.x;
  const int lane = tid & 63;
  const int wid  = tid >> 6;
  const int bat  = wg >> 7;       // batch 0..3
  const int slab = wg & 127;      // row slab within batch

  unsigned* leaf   = (unsigned*)(ws);          // 2048B
  unsigned* root   = (unsigned*)(ws + 2048);
  unsigned* gen    = (unsigned*)(ws + 2052);
  float*    err_sq = (float*)(ws + 2056);      // [2]
  unsigned* stmax  = (unsigned*)(ws + 2064);   // [2] float bits (all values >= 0)
  float*    amaxa  = (float*)(ws + 2080);      // [512]
  float*    bn_g   = (float*)(ws + 4128);      // [4*513]

  __shared__ float Klds[RPW][KP1];
  __shared__ float ev[KP1], vv[KP1], bb[KP1], lb[KP1], ww[KC];
  __shared__ float u_s[RPW], kap[RPW], a_s[RPW], alp[RPW];
  __shared__ float wred[4];
  __shared__ float colred[4][64];

  // ---------------- phase 0: init state + build K in LDS ----------------
  for (int j = tid; j < KP1; j += NTHR) {
    vv[j] = 0.f; bb[j] = 1.f / 513.f; lb[j] = 1.f / 513.f;
    if (j < KC) ww[j] = 1.f;
  }
  if (tid < RPW) { u_s[tid] = 0.f; kap[tid] = 1.f; a_s[tid] = 0.f; alp[tid] = 0.f; }

  const size_t rowg0 = (size_t)bat * NROW + (size_t)slab * RPW;
  for (int r = wid; r < RPW; r += 4) {
    const float* lp = logits + (rowg0 + (size_t)r) * KC;
    float x[8];
    float mx = -INFINITY;
#pragma unroll
    for (int m = 0; m < 8; ++m) { x[m] = lp[lane + (m << 6)]; mx = fmaxf(mx, x[m]); }
    mx = wmaxf(mx);
    float sm = 0.f;
#pragma unroll
    for (int m = 0; m < 8; ++m) sm += expf(x[m] - mx);
    sm = wsum(sm);
    float lse = mx + logf(sm);
#pragma unroll
    for (int m = 0; m < 8; ++m) Klds[r][lane + (m << 6)] = expf((x[m] - lse) * IEPS);
    if (lane == 0) Klds[r][KC] = 1.f;   // slack column: C=0 -> K=1
  }
  __syncthreads();

  // ---------------- iterations ----------------
  float err_state = 1.f;
  int   stabled = 0;
  int   pend = -1;

  auto apply = [&](int par_) {
    float esq = err_sq[par_];
    int stab = (__uint_as_float(stmax[par_]) > STABT) ? 1 : 0;
    for (int j = tid; j < KP1; j += NTHR) {
      float bnj = bn_g[bat * KP1 + j];
      if (stab) {
        vv[j] += EPSI * logf(bnj + TINY);
        if (j < KC) ww[j] *= powf(fmaxf(bnj, TINY), FIM1);
        bb[j] = 1.f;
      } else {
        bb[j] = bnj;
      }
      lb[j] = bnj;
    }
    if (stab && tid < RPW) {
      u_s[tid] += EPSI * logf(a_s[tid]);
      kap[tid] = expf(u_s[tid] * IEPS);
    }
    err_state = sqrtf(esq);
    stabled = stab;
    __syncthreads();
  };

  for (int t = 0; t < ITMAX; ++t) {
    if (pend >= 0) { apply(pend); pend = -1; }
    if (!(err_state > STOPE)) break;     // uniform across grid

    // ---- phase A: ev, row sums -> a, alpha; col partials ----
    for (int j = tid; j < KP1; j += NTHR) ev[j] = expf(vv[j] * IEPS) * bb[j];
    __syncthreads();

    float wamax = 0.f;
    for (int r = wid; r < RPW; r += 4) {
      float s = 0.f;
#pragma unroll
      for (int m = 0; m < 8; ++m) { int j = lane + (m << 6); s += Klds[r][j] * ev[j]; }
      if (lane == 0) s += Klds[r][KC] * ev[KC];
      s = wsum(s);
      if (lane == 0) {
        float av = PA / (kap[r] * s);
        a_s[r] = av; alp[r] = kap[r] * av;
        wamax = fmaxf(wamax, av);
      }
    }
    if (lane == 0) wred[wid] = wamax;
    __syncthreads();
    if (tid == 0) amaxa[wg] = fmaxf(fmaxf(wred[0], wred[1]), fmaxf(wred[2], wred[3]));

    for (int j = tid; j < KP1; j += NTHR) {
      float acc = 0.f;
#pragma unroll
      for (int r = 0; r < RPW; ++r) acc += Klds[r][j] * alp[r];
      partials[((size_t)bat * SLABS + slab) * KP1 + j] = acc;
    }
    gbar(leaf, root, gen);

    // ---- phase B: column sums -> bn, err, stab-max ----
    const int par = t & 1;
    {
      int j = (slab < 9) ? (slab * 64 + lane) : KP1;   // WG-uniform owner branch
      float acc = 0.f;
      if (j < KP1) {
        const float* pbase = partials + (size_t)bat * SLABS * KP1 + j;
        for (int s = wid * 32; s < wid * 32 + 32; ++s) acc += pbase[(size_t)s * KP1];
      }
      colred[wid][lane] = acc;
      __syncthreads();
      if (slab < 9 && wid == 0) {
        float esql = 0.f, bmx = 0.f;
        if (j < KP1) {
          float tot = colred[0][lane] + colred[1][lane] + colred[2][lane] + colred[3][lane];
          float c = expf(vv[j] * IEPS) * tot;
          float pb = (j < KC) ? PBR : PBS;
          float bnr = pb / c;
          float bnj = (j < KC) ? powf(fmaxf(bnr, TINY), FI) * ww[j] : bnr;
          bn_g[bat * KP1 + j] = bnj;
          float d = bnj - lb[j];
          esql = d * d; bmx = bnj;
        }
        esql = wsum(esql); bmx = wmaxf(bmx);
        if (lane == 0) {
          atomicAdd(&err_sq[par], esql);
          atomicMax(&stmax[par], __float_as_uint(bmx));
        }
      }
    }
    if (wg == 9 && wid == 1) {   // global a-max (amaxa written in phase A, pre-S1)
      float m = 0.f;
      for (int i = lane; i < NWG; i += 64) m = fmaxf(m, amaxa[i]);
      m = wmaxf(m);
      if (lane == 0) atomicMax(&stmax[par], __float_as_uint(m));
    }
    if (wg == 10 && tid == 0) {  // zero next-parity accumulators (consumed pre-S1)
      __hip_atomic_store(&err_sq[par ^ 1], 0.f, __ATOMIC_RELAXED, __HIP_MEMORY_SCOPE_AGENT);
      __hip_atomic_store(&stmax[par ^ 1], 0u, __ATOMIC_RELAXED, __HIP_MEMORY_SCOPE_AGENT);
    }
    gbar(leaf, root, gen);
    pend = par;
  }
  if (pend >= 0) { apply(pend); pend = -1; }

  // ---------------- final: plan = (stabled ? Q : a*Q*b^T) * n, drop slack ----------------
  for (int j = tid; j < KP1; j += NTHR) ev[j] = expf(vv[j] * IEPS);
  __syncthreads();
  for (int r = wid; r < RPW; r += 4) {
    float* op = out + (rowg0 + (size_t)r) * KC;
    float kr = kap[r], ar = a_s[r];
#pragma unroll
    for (int m = 0; m < 8; ++m) {
      int j = lane + (m << 6);
      float Q = kr * Klds[r][j] * ev[j];
      float val = stabled ? Q : (ar * Q * bb[j]);
      op[j] = val * 2048.0f;
    }
  }
}

extern "C" void kernel_launch(void* const* d_in, const int* in_sizes, int n_in,
                              void* d_out, int out_size, void* d_ws, size_t ws_size,
                              hipStream_t stream) {
  (void)in_sizes; (void)n_in; (void)out_size; (void)ws_size;
  const float* logits = (const float*)d_in[0];
  float* out = (float*)d_out;
  // barrier counters + gen + err/stab scalars must start at 0 each launch
  (void)hipMemsetAsync(d_ws, 0, 2080, stream);
  // partials buffer (4*128*513 floats = 1.05MB) carved from d_out; it is only
  // overwritten by the final plan store, which happens after the last barrier.
  sinkhorn_kernel<<<dim3(NWG), dim3(NTHR), 0, stream>>>(
      logits, out, (unsigned char*)d_ws, (float*)d_out);
}

// Round 4
// 681.718 us; speedup vs baseline: 6.5946x; 3.0157x over previous
//
#include <hip/hip_runtime.h>
#include <math.h>

// SemiCurrSinkhornKnopp_stable on MI355X: persistent cooperative-style kernel.
// B=4, n=2048, k=512 (+1 slack). K = exp(-C/eps) = softmax(logits)^10 kept in LDS.
// 512 WGs x 256 thr; 16 rows/WG; 2 grid barriers per iteration.
// R4: fence-FREE sync. All cross-WG data uses agent-scope relaxed atomics
// (sc1 -> coherent LLC, bypasses non-coherent XCD L2). No buffer_wbl2/buffer_inv
// at all (R3's 2x512 fences/barrier = L2 walk storm, ~20us/barrier).
// Release broadcast distributed over 32 ggen lines (16 pollers/line).

#define NWG   512
#define NTHR  256
#define NROW  2048
#define KC    512
#define KP1   513
#define SLABS 128          // row slabs per batch (128 * 16 = 2048)
#define RPW   16           // rows per workgroup
#define EPSI  0.1f
#define IEPS  10.0f
#define FI    0.90909090909090906f     // gamma/(gamma+eps), f32-rounded like jnp
#define FIM1  (-0.09090909090909094f)  // fi - 1.0
#define TINY  1.1920928955078125e-07f  // finfo(f32).eps
#define PA    (1.0f/2048.0f)
#define PBR   (0.5f/512.0f)
#define PBS   0.5f
#define STABT 1.0e8f
#define STOPE 1.0e-6f
#define ITMAX 50

#define AST(p, v)  __hip_atomic_store((p), (v), __ATOMIC_RELAXED, __HIP_MEMORY_SCOPE_AGENT)
#define ALD(p)     __hip_atomic_load((p), __ATOMIC_RELAXED, __HIP_MEMORY_SCOPE_AGENT)

__device__ __forceinline__ float wsum(float v) {
#pragma unroll
  for (int m = 32; m > 0; m >>= 1) v += __shfl_xor(v, m, 64);
  return v;
}
__device__ __forceinline__ float wmaxf(float v) {
#pragma unroll
  for (int m = 32; m > 0; m >>= 1) v = fmaxf(v, __shfl_xor(v, m, 64));
  return v;
}

// Two-level grid barrier, fence-free. Counters monotonic, host-zeroed per launch.
// __syncthreads() drains each wave's vmcnt (sc1 stores reach LLC) before arrive.
// mygen is a per-WG local generation (uniform control flow keeps it aligned).
__device__ __forceinline__ void gbar(unsigned* leaf, unsigned* root, unsigned* ggen,
                                     unsigned mygen) {
  __syncthreads();
  if (threadIdx.x == 0) {
    asm volatile("s_waitcnt vmcnt(0)" ::: "memory");
    unsigned* lc = leaf + ((blockIdx.x >> 4) << 4);   // stride 16 u32 = 64B
    unsigned p1 = __hip_atomic_fetch_add(lc, 1u, __ATOMIC_RELAXED, __HIP_MEMORY_SCOPE_AGENT);
    if ((p1 & 15u) == 15u) {
      unsigned p2 = __hip_atomic_fetch_add(root, 1u, __ATOMIC_RELAXED, __HIP_MEMORY_SCOPE_AGENT);
      if ((p2 & 31u) == 31u) {
#pragma unroll
        for (int i = 0; i < 32; ++i) AST(ggen + i * 16, mygen);
      }
    }
    unsigned* mg = ggen + ((blockIdx.x >> 4) << 4);
    while (ALD(mg) < mygen) __builtin_amdgcn_s_sleep(8);
  }
  __syncthreads();
}

__global__ __launch_bounds__(NTHR, 2)
void sinkhorn_kernel(const float* __restrict__ logits, float* __restrict__ out,
                     unsigned char* __restrict__ ws, float* __restrict__ partials) {
  const int tid  = threadIdx.x;
  const int wg   = blockIdx.x;
  const int lane = tid & 63;
  const int wid  = tid >> 6;
  const int bat  = wg >> 7;       // batch 0..3
  const int slab = wg & 127;      // row slab within batch

  unsigned* leaf   = (unsigned*)(ws);          // 32 lines x 64B = 2048B
  unsigned* root   = (unsigned*)(ws + 2048);
  unsigned* ggen   = (unsigned*)(ws + 2112);   // 32 lines x 64B = 2048B
  float*    err_sq = (float*)(ws + 4160);      // [2]
  unsigned* stmax  = (unsigned*)(ws + 4168);   // [2] float bits (values >= 0)
  float*    amaxa  = (float*)(ws + 4224);      // [512]
  float*    bn_g   = (float*)(ws + 6272);      // [4*513]

  __shared__ float Klds[RPW][KP1];
  __shared__ float ev[KP1], vv[KP1], bb[KP1], lb[KP1], ww[KC];
  __shared__ float u_s[RPW], kap[RPW], a_s[RPW], alp[RPW];
  __shared__ float wred[4];
  __shared__ float colred[4][64];

  // ---------------- phase 0: init state + build K in LDS ----------------
  for (int j = tid; j < KP1; j += NTHR) {
    vv[j] = 0.f; bb[j] = 1.f / 513.f; lb[j] = 1.f / 513.f;
    if (j < KC) ww[j] = 1.f;
  }
  if (tid < RPW) { u_s[tid] = 0.f; kap[tid] = 1.f; a_s[tid] = 0.f; alp[tid] = 0.f; }

  const size_t rowg0 = (size_t)bat * NROW + (size_t)slab * RPW;
  for (int r = wid; r < RPW; r += 4) {
    const float* lp = logits + (rowg0 + (size_t)r) * KC;
    float x[8];
    float mx = -INFINITY;
#pragma unroll
    for (int m = 0; m < 8; ++m) { x[m] = lp[lane + (m << 6)]; mx = fmaxf(mx, x[m]); }
    mx = wmaxf(mx);
    float sm = 0.f;
#pragma unroll
    for (int m = 0; m < 8; ++m) sm += expf(x[m] - mx);
    sm = wsum(sm);
    float lse = mx + logf(sm);
#pragma unroll
    for (int m = 0; m < 8; ++m) Klds[r][lane + (m << 6)] = expf((x[m] - lse) * IEPS);
    if (lane == 0) Klds[r][KC] = 1.f;   // slack column: C=0 -> K=1
  }
  __syncthreads();

  // ---------------- iterations ----------------
  float err_state = 1.f;
  int   stabled = 0;
  int   pend = -1;
  unsigned bargen = 0;

  auto apply = [&](int par_) {
    float esq = ALD(&err_sq[par_]);
    int stab = (__uint_as_float(ALD(&stmax[par_])) > STABT) ? 1 : 0;
    for (int j = tid; j < KP1; j += NTHR) {
      float bnj = ALD(&bn_g[bat * KP1 + j]);
      if (stab) {
        vv[j] += EPSI * logf(bnj + TINY);
        if (j < KC) ww[j] *= powf(fmaxf(bnj, TINY), FIM1);
        bb[j] = 1.f;
      } else {
        bb[j] = bnj;
      }
      lb[j] = bnj;
    }
    if (stab && tid < RPW) {
      u_s[tid] += EPSI * logf(a_s[tid]);
      kap[tid] = expf(u_s[tid] * IEPS);
    }
    err_state = sqrtf(esq);
    stabled = stab;
    __syncthreads();
  };

  for (int t = 0; t < ITMAX; ++t) {
    if (pend >= 0) { apply(pend); pend = -1; }
    if (!(err_state > STOPE)) break;     // uniform across grid

    // ---- phase A: ev, row sums -> a, alpha; col partials ----
    for (int j = tid; j < KP1; j += NTHR) ev[j] = expf(vv[j] * IEPS) * bb[j];
    __syncthreads();

    float wamax = 0.f;
    for (int r = wid; r < RPW; r += 4) {
      float s = 0.f;
#pragma unroll
      for (int m = 0; m < 8; ++m) { int j = lane + (m << 6); s += Klds[r][j] * ev[j]; }
      if (lane == 0) s += Klds[r][KC] * ev[KC];
      s = wsum(s);
      if (lane == 0) {
        float av = PA / (kap[r] * s);
        a_s[r] = av; alp[r] = kap[r] * av;
        wamax = fmaxf(wamax, av);
      }
    }
    if (lane == 0) wred[wid] = wamax;
    __syncthreads();
    if (tid == 0) AST(&amaxa[wg], fmaxf(fmaxf(wred[0], wred[1]), fmaxf(wred[2], wred[3])));

    for (int j = tid; j < KP1; j += NTHR) {
      float acc = 0.f;
#pragma unroll
      for (int r = 0; r < RPW; ++r) acc += Klds[r][j] * alp[r];
      AST(&partials[((size_t)bat * SLABS + slab) * KP1 + j], acc);
    }
    gbar(leaf, root, ggen, ++bargen);

    // ---- phase B: column sums -> bn, err, stab-max ----
    const int par = t & 1;
    {
      int j = (slab < 9) ? (slab * 64 + lane) : KP1;   // WG-uniform owner branch
      float acc = 0.f;
      if (j < KP1) {
        const float* pbase = partials + (size_t)bat * SLABS * KP1 + j;
        for (int s = wid * 32; s < wid * 32 + 32; ++s) acc += ALD(&pbase[(size_t)s * KP1]);
      }
      colred[wid][lane] = acc;
      __syncthreads();
      if (slab < 9 && wid == 0) {
        float esql = 0.f, bmx = 0.f;
        if (j < KP1) {
          float tot = colred[0][lane] + colred[1][lane] + colred[2][lane] + colred[3][lane];
          float c = expf(vv[j] * IEPS) * tot;
          float pb = (j < KC) ? PBR : PBS;
          float bnr = pb / c;
          float bnj = (j < KC) ? powf(fmaxf(bnr, TINY), FI) * ww[j] : bnr;
          AST(&bn_g[bat * KP1 + j], bnj);
          float d = bnj - lb[j];
          esql = d * d; bmx = bnj;
        }
        esql = wsum(esql); bmx = wmaxf(bmx);
        if (lane == 0) {
          atomicAdd(&err_sq[par], esql);
          atomicMax(&stmax[par], __float_as_uint(bmx));
        }
      }
    }
    if (wg == 9 && wid == 1) {   // global a-max (amaxa written in phase A, pre-S1)
      float m = 0.f;
      for (int i = lane; i < NWG; i += 64) m = fmaxf(m, ALD(&amaxa[i]));
      m = wmaxf(m);
      if (lane == 0) atomicMax(&stmax[par], __float_as_uint(m));
    }
    if (wg == 10 && tid == 0) {  // zero next-parity accumulators (consumed pre-S1)
      AST(&err_sq[par ^ 1], 0.f);
      AST(&stmax[par ^ 1], 0u);
    }
    gbar(leaf, root, ggen, ++bargen);
    pend = par;
  }
  if (pend >= 0) { apply(pend); pend = -1; }

  // ---------------- final: plan = (stabled ? Q : a*Q*b^T) * n, drop slack ----------------
  for (int j = tid; j < KP1; j += NTHR) ev[j] = expf(vv[j] * IEPS);
  __syncthreads();
  for (int r = wid; r < RPW; r += 4) {
    float* op = out + (rowg0 + (size_t)r) * KC;
    float kr = kap[r], ar = a_s[r];
#pragma unroll
    for (int m = 0; m < 8; ++m) {
      int j = lane + (m << 6);
      float Q = kr * Klds[r][j] * ev[j];
      float val = stabled ? Q : (ar * Q * bb[j]);
      op[j] = val * 2048.0f;
    }
  }
}

extern "C" void kernel_launch(void* const* d_in, const int* in_sizes, int n_in,
                              void* d_out, int out_size, void* d_ws, size_t ws_size,
                              hipStream_t stream) {
  (void)in_sizes; (void)n_in; (void)out_size; (void)ws_size;
  const float* logits = (const float*)d_in[0];
  float* out = (float*)d_out;
  // barrier counters + ggen + err/stab scalars must start at 0 each launch
  (void)hipMemsetAsync(d_ws, 0, 4224, stream);
  // partials buffer (4*128*513 floats = 1.05MB) carved from d_out; it is only
  // overwritten by the final plan store, which happens after the last barrier.
  sinkhorn_kernel<<<dim3(NWG), dim3(NTHR), 0, stream>>>(
      logits, out, (unsigned char*)d_ws, (float*)d_out);
}